// Round 2
// baseline (16370.772 us; speedup 1.0000x reference)
//
#include <hip/hip_runtime.h>
#include <math.h>

#define VOCAB 32000
#define HID   1024
#define BATCH 8
#define SEQ   512
#define GD    (4*HID)       // 4096 gate width
#define ROWS  (BATCH*SEQ)   // 4096

// ---------------------------------------------------------------------------
// 1) Embedding gather: emb[row][h] = w_out[h][ids[row]]
// ---------------------------------------------------------------------------
__global__ __launch_bounds__(256) void k_gather(const int* __restrict__ ids,
                                                const float* __restrict__ w_out,
                                                float* __restrict__ emb)
{
    int row = blockIdx.x;            // 0..4095  (b*SEQ + s)
    int id  = ids[row];
    const float* src = w_out + id;   // column id, stride VOCAB
    float* dst = emb + (size_t)row * HID;
    for (int h = threadIdx.x; h < HID; h += 256)
        dst[h] = src[(size_t)h * VOCAB];
}

// ---------------------------------------------------------------------------
// 2) Transpose W_hh [1024][4096] -> W_hhT [4096][1024]
// ---------------------------------------------------------------------------
__global__ __launch_bounds__(256) void k_transpose(const float* __restrict__ W,
                                                   float* __restrict__ WT)
{
    __shared__ float tile[32][33];
    int bx = blockIdx.x;  // over 4096 cols /32
    int by = blockIdx.y;  // over 1024 rows /32
    int x = bx*32 + threadIdx.x;
    int y = by*32 + threadIdx.y;
    #pragma unroll
    for (int i = 0; i < 32; i += 8)
        tile[threadIdx.y + i][threadIdx.x] = W[(size_t)(y + i)*GD + x];
    __syncthreads();
    int k   = by*32 + threadIdx.x;   // 1024-dim index
    int col = bx*32 + threadIdx.y;   // 4096-dim index
    #pragma unroll
    for (int i = 0; i < 32; i += 8)
        WT[(size_t)(col + i)*HID + k] = tile[threadIdx.x][threadIdx.y + i];
}

// ---------------------------------------------------------------------------
// 3) fp32 tiled GEMM + bias: C[M][N] = A[M][K] @ B[K][N] + bias[N]
//    BM=BN=128, BK=32, 256 threads, 8x8 per thread.
// ---------------------------------------------------------------------------
#define BM 128
#define BN 128
#define BKK 32
#define TM 8
#define TN 8

__global__ __launch_bounds__(256) void k_gemm_bias(const float* __restrict__ A,
                                                   const float* __restrict__ B,
                                                   const float* __restrict__ bias,
                                                   float* __restrict__ C,
                                                   int M, int N, int K)
{
    __shared__ float As[BKK][BM + 4];   // transposed: As[k][m]
    __shared__ float Bs[BKK][BN];

    int tid  = threadIdx.x;
    int brow = blockIdx.y * BM;
    int bcol = blockIdx.x * BN;

    int a_m = tid >> 3;
    int a_k = (tid & 7) * 4;
    int b_k = tid >> 5;
    int b_n = (tid & 31) * 4;

    int tm = (tid >> 4) * TM;
    int tn = (tid & 15) * TN;

    float acc[TM][TN] = {};

    for (int k0 = 0; k0 < K; k0 += BKK) {
        #pragma unroll
        for (int p = 0; p < 4; ++p) {
            int m = a_m + p*32;
            float4 v = *(const float4*)(A + (size_t)(brow + m)*K + k0 + a_k);
            As[a_k + 0][m] = v.x;
            As[a_k + 1][m] = v.y;
            As[a_k + 2][m] = v.z;
            As[a_k + 3][m] = v.w;
        }
        #pragma unroll
        for (int p = 0; p < 4; ++p) {
            int kk = b_k + p*8;
            *(float4*)(&Bs[kk][b_n]) =
                *(const float4*)(B + (size_t)(k0 + kk)*N + bcol + b_n);
        }
        __syncthreads();

        #pragma unroll
        for (int kk = 0; kk < BKK; ++kk) {
            float a[TM], b[TN];
            *(float4*)&a[0] = *(const float4*)&As[kk][tm];
            *(float4*)&a[4] = *(const float4*)&As[kk][tm + 4];
            *(float4*)&b[0] = *(const float4*)&Bs[kk][tn];
            *(float4*)&b[4] = *(const float4*)&Bs[kk][tn + 4];
            #pragma unroll
            for (int i = 0; i < TM; ++i)
                #pragma unroll
                for (int j = 0; j < TN; ++j)
                    acc[i][j] += a[i] * b[j];
        }
        __syncthreads();
    }

    float4 bv0 = *(const float4*)(bias + bcol + tn);
    float4 bv1 = *(const float4*)(bias + bcol + tn + 4);
    #pragma unroll
    for (int i = 0; i < TM; ++i) {
        int row = brow + tm + i;
        float4* cp = (float4*)(C + (size_t)row*N + bcol + tn);
        float4 o0, o1;
        o0.x = acc[i][0] + bv0.x; o0.y = acc[i][1] + bv0.y;
        o0.z = acc[i][2] + bv0.z; o0.w = acc[i][3] + bv0.w;
        o1.x = acc[i][4] + bv1.x; o1.y = acc[i][5] + bv1.y;
        o1.z = acc[i][6] + bv1.z; o1.w = acc[i][7] + bv1.w;
        cp[0] = o0; cp[1] = o1;
    }
}

// ---------------------------------------------------------------------------
// 4) One LSTM timestep — RACE-FREE version.
//    Previous h is read from hs[b][t-1][*] (written last launch); new h is
//    written to hs[b][t][*]. Disjoint regions -> no intra-launch hazard.
//    Grid: 256 blocks, block owns 4 hidden columns (j0 = blockIdx.x*4).
//    Thread layout (256): b(8) x gate(4) x jl(4) x ks(2).
//    Each thread computes half the K=1024 dot; pair-reduced via shfl_xor.
// ---------------------------------------------------------------------------
__global__ __launch_bounds__(256) void k_lstm_step(const float* __restrict__ xg,
                                                   const float* __restrict__ WT,
                                                   float* __restrict__ c_state,
                                                   float* __restrict__ hs,
                                                   int t)
{
    int tid  = threadIdx.x;
    int b    = tid >> 5;          // 0..7
    int gate = (tid >> 3) & 3;    // 0..3  (i,f,g,o)
    int jl   = (tid >> 1) & 3;    // 0..3
    int ks   = tid & 1;           // 0..1  K-split half
    int j0   = blockIdx.x * 4;
    int col  = gate*HID + j0 + jl;

    float acc = 0.0f;
    if (t > 0) {
        const float4* hv = (const float4*)(hs + ((size_t)b*SEQ + (t-1))*HID)
                           + ks * (HID/8);
        const float4* wv = (const float4*)(WT + (size_t)col*HID)
                           + ks * (HID/8);
        #pragma unroll 8
        for (int k4 = 0; k4 < HID/8; ++k4) {   // 128 float4 each half
            float4 h4 = hv[k4];
            float4 w4 = wv[k4];
            acc += h4.x*w4.x + h4.y*w4.y + h4.z*w4.z + h4.w*w4.w;
        }
    }
    acc += __shfl_xor(acc, 1);    // combine the two K halves

    __shared__ float g_sm[BATCH][4][4];
    if (ks == 0)
        g_sm[b][gate][jl] = acc + xg[(size_t)(b*SEQ + t)*GD + col];
    __syncthreads();

    if (tid < 32) {
        int bb = tid >> 2;        // 0..7
        int j  = tid & 3;         // 0..3
        float iv = g_sm[bb][0][j];
        float fv = g_sm[bb][1][j];
        float gv = g_sm[bb][2][j];
        float ov = g_sm[bb][3][j];
        iv = 1.0f / (1.0f + expf(-iv));
        fv = 1.0f / (1.0f + expf(-fv));
        gv = tanhf(gv);
        ov = 1.0f / (1.0f + expf(-ov));
        float c  = (t > 0) ? c_state[(size_t)bb*HID + j0 + j] : 0.0f;
        float cn = fv*c + iv*gv;
        float hn = ov * tanhf(cn);
        c_state[(size_t)bb*HID + j0 + j] = cn;
        hs[((size_t)bb*SEQ + t)*HID + j0 + j] = hn;
    }
}

// ---------------------------------------------------------------------------
// Launch
// ---------------------------------------------------------------------------
extern "C" void kernel_launch(void* const* d_in, const int* in_sizes, int n_in,
                              void* d_out, int out_size, void* d_ws, size_t ws_size,
                              hipStream_t stream)
{
    const int*   ids    = (const int*)  d_in[0];
    const float* w_out  = (const float*)d_in[1];
    const float* b_out  = (const float*)d_in[2];
    const float* W_ih   = (const float*)d_in[3];
    const float* W_hh   = (const float*)d_in[4];
    const float* b_lstm = (const float*)d_in[5];
    float* out = (float*)d_out;

    // Scratch carved from d_out (524 MB; every region dead before the final
    // GEMM overwrites d_out). hs (read during the final GEMM) lives in d_ws.
    char* ob = (char*)d_out;
    float* emb    = (float*)(ob);                 // 16,777,216 B
    float* WT     = (float*)(ob + 16777216);      // 16,777,216 B
    float* xg     = (float*)(ob + 33554432);      // 67,108,864 B
    float* cstate = (float*)(ob + 100663296);     // 32,768 B
    float* hs     = (float*)d_ws;                 // 16,777,216 B

    // 1) embedding gather
    k_gather<<<ROWS, 256, 0, stream>>>(ids, w_out, emb);

    // 2) transpose W_hh for contiguous per-column dots in the scan
    k_transpose<<<dim3(GD/32, HID/32), dim3(32, 8), 0, stream>>>(W_hh, WT);

    // 3) x_gates = emb @ W_ih + b_lstm   [4096 x 4096]
    k_gemm_bias<<<dim3(GD/BN, ROWS/BM), 256, 0, stream>>>(
        emb, W_ih, b_lstm, xg, ROWS, GD, HID);

    // 4) sequential LSTM scan: 512 launches, race-free (hs ping via t index)
    for (int t = 0; t < SEQ; ++t)
        k_lstm_step<<<HID/4, 256, 0, stream>>>(xg, WT, cstate, hs, t);

    // 5) logits = hs @ w_out + b_out   [4096 x 32000]
    k_gemm_bias<<<dim3(VOCAB/BN, ROWS/BM), 256, 0, stream>>>(
        hs, w_out, b_out, out, ROWS, VOCAB, HID);
}

// Round 3
// 13499.741 us; speedup vs baseline: 1.2127x; 1.2127x over previous
//
#include <hip/hip_runtime.h>
#include <math.h>

#define VOCAB 32000
#define HID   1024
#define BATCH 8
#define SEQ   512
#define GD    (4*HID)       // 4096 gate width
#define ROWS  (BATCH*SEQ)   // 4096

typedef __attribute__((ext_vector_type(8))) short short8;
typedef __attribute__((ext_vector_type(4))) float f32x4;

// ---------------------------------------------------------------------------
// 1) Embedding gather: emb[row][h] = w_out[h][ids[row]]
// ---------------------------------------------------------------------------
__global__ __launch_bounds__(256) void k_gather(const int* __restrict__ ids,
                                                const float* __restrict__ w_out,
                                                float* __restrict__ emb)
{
    int row = blockIdx.x;            // 0..4095  (b*SEQ + s)
    int id  = ids[row];
    const float* src = w_out + id;   // column id, stride VOCAB
    float* dst = emb + (size_t)row * HID;
    for (int h = threadIdx.x; h < HID; h += 256)
        dst[h] = src[(size_t)h * VOCAB];
}

// ---------------------------------------------------------------------------
// 2) Transpose W_hh [1024][4096] -> W_hhT [4096][1024]
// ---------------------------------------------------------------------------
__global__ __launch_bounds__(256) void k_transpose(const float* __restrict__ W,
                                                   float* __restrict__ WT)
{
    __shared__ float tile[32][33];
    int bx = blockIdx.x;
    int by = blockIdx.y;
    int x = bx*32 + threadIdx.x;
    int y = by*32 + threadIdx.y;
    #pragma unroll
    for (int i = 0; i < 32; i += 8)
        tile[threadIdx.y + i][threadIdx.x] = W[(size_t)(y + i)*GD + x];
    __syncthreads();
    int k   = by*32 + threadIdx.x;
    int col = bx*32 + threadIdx.y;
    #pragma unroll
    for (int i = 0; i < 32; i += 8)
        WT[(size_t)(col + i)*HID + k] = tile[threadIdx.x][threadIdx.y + i];
}

// ---------------------------------------------------------------------------
// 3) Split-bf16 MFMA GEMM + bias:  C = A(f32)·B(f32) + bias
//    A:[M][K] row-major, B:[K][N] row-major, all % {128,128,32} == 0.
//    fp32 x = hi(bf16,trunc) + lo(bf16,trunc of exact residual)
//    C ≈ Ahi·Bhi + Ahi·Blo + Alo·Bhi   (err ~2^-16 rel)
//    Block: 256 thr = 4 waves (2x2), 128x128 tile, BK=32.
// ---------------------------------------------------------------------------
#define GBM 128
#define GBN 128
#define GBK 32

__device__ __forceinline__ unsigned pack_hi(float x, float y) {
    return (__float_as_uint(x) >> 16) | (__float_as_uint(y) & 0xFFFF0000u);
}
__device__ __forceinline__ float hi_f32(float x) {
    return __uint_as_float(__float_as_uint(x) & 0xFFFF0000u);
}
// packed word: hi bf16 in high half, lo bf16 in low half
__device__ __forceinline__ unsigned pack_pair(float x) {
    unsigned hb = __float_as_uint(x) & 0xFFFF0000u;
    float lo = x - __uint_as_float(hb);
    return hb | (__float_as_uint(lo) >> 16);
}

__global__ __launch_bounds__(256) void k_gemm_mfma(const float* __restrict__ A,
                                                   const float* __restrict__ B,
                                                   const float* __restrict__ bias,
                                                   float* __restrict__ C,
                                                   int M, int N, int K)
{
    // As rows padded to 40 bf16 (80 B, 16B-aligned); Bs rows 130 u32 words.
    __shared__ unsigned short As_hi[GBM][40];
    __shared__ unsigned short As_lo[GBM][40];
    __shared__ unsigned int   Bs[GBK][130];

    int tid  = threadIdx.x;
    int brow = blockIdx.y * GBM;
    int bcol = blockIdx.x * GBN;

    int lane = tid & 63;
    int wid  = tid >> 6;
    int wm   = wid >> 1;          // 0..1
    int wn   = wid & 1;           // 0..1
    int l15  = lane & 15;
    int l4   = lane >> 4;         // 0..3

    // staging coords
    int a_m = tid >> 3;           // 0..31
    int a_c = tid & 7;            // float4 index in k (0..7)
    int b_k = tid >> 5;           // 0..7
    int b_n = tid & 31;           // float4 index in n (0..31)

    f32x4 acc[4][4] = {};

    for (int k0 = 0; k0 < K; k0 += GBK) {
        // ---- stage A: 128x32 f32 -> hi/lo bf16 LDS ----
        #pragma unroll
        for (int p = 0; p < 4; ++p) {
            int r = a_m + p*32;
            float4 v = *(const float4*)(A + (size_t)(brow + r)*K + k0 + a_c*4);
            unsigned h0 = pack_hi(v.x, v.y);
            unsigned h1 = pack_hi(v.z, v.w);
            float lx = v.x - hi_f32(v.x);
            float ly = v.y - hi_f32(v.y);
            float lz = v.z - hi_f32(v.z);
            float lw = v.w - hi_f32(v.w);
            unsigned l0 = pack_hi(lx, ly);
            unsigned l1 = pack_hi(lz, lw);
            *(uint2*)&As_hi[r][a_c*4] = make_uint2(h0, h1);
            *(uint2*)&As_lo[r][a_c*4] = make_uint2(l0, l1);
        }
        // ---- stage B: 32x128 f32 -> packed (hi|lo) u32 LDS ----
        #pragma unroll
        for (int p = 0; p < 4; ++p) {
            int kk = b_k + p*8;
            float4 v = *(const float4*)(B + (size_t)(k0 + kk)*N + bcol + b_n*4);
            unsigned w0 = pack_pair(v.x);
            unsigned w1 = pack_pair(v.y);
            unsigned w2 = pack_pair(v.z);
            unsigned w3 = pack_pair(v.w);
            *(uint2*)&Bs[kk][b_n*4]     = make_uint2(w0, w1);
            *(uint2*)&Bs[kk][b_n*4 + 2] = make_uint2(w2, w3);
        }
        __syncthreads();

        // ---- A fragments: 8 x ds_read_b128 ----
        short8 ah[4], al[4];
        #pragma unroll
        for (int m = 0; m < 4; ++m) {
            int r = wm*64 + m*16 + l15;
            ah[m] = *(const short8*)&As_hi[r][l4*8];
            al[m] = *(const short8*)&As_lo[r][l4*8];
        }

        // ---- per n-frag: gather 8 packed words, unpack, 12 MFMAs ----
        #pragma unroll
        for (int n = 0; n < 4; ++n) {
            int col = wn*64 + n*16 + l15;
            unsigned w[8];
            #pragma unroll
            for (int j = 0; j < 8; ++j)
                w[j] = Bs[l4*8 + j][col];
            union { short8 v; unsigned d[4]; } bh, bl;
            #pragma unroll
            for (int d = 0; d < 4; ++d) {
                bh.d[d] = (w[2*d] >> 16)      | (w[2*d+1] & 0xFFFF0000u);
                bl.d[d] = (w[2*d] & 0xFFFFu)  | (w[2*d+1] << 16);
            }
            #pragma unroll
            for (int m = 0; m < 4; ++m) {
                acc[m][n] = __builtin_amdgcn_mfma_f32_16x16x32_bf16(ah[m], bh.v, acc[m][n], 0, 0, 0);
                acc[m][n] = __builtin_amdgcn_mfma_f32_16x16x32_bf16(ah[m], bl.v, acc[m][n], 0, 0, 0);
                acc[m][n] = __builtin_amdgcn_mfma_f32_16x16x32_bf16(al[m], bh.v, acc[m][n], 0, 0, 0);
            }
        }
        __syncthreads();
    }

    // ---- epilogue: C = acc + bias ----
    #pragma unroll
    for (int n = 0; n < 4; ++n) {
        int col = bcol + wn*64 + n*16 + l15;
        float bv = bias[col];
        #pragma unroll
        for (int m = 0; m < 4; ++m) {
            int rb = brow + wm*64 + m*16 + l4*4;
            #pragma unroll
            for (int r = 0; r < 4; ++r)
                C[(size_t)(rb + r)*N + col] = acc[m][n][r] + bv;
        }
    }
}

// ---------------------------------------------------------------------------
// 4) One LSTM timestep — race-free (reads hs[t-1], writes hs[t]).
// ---------------------------------------------------------------------------
__global__ __launch_bounds__(256) void k_lstm_step(const float* __restrict__ xg,
                                                   const float* __restrict__ WT,
                                                   float* __restrict__ c_state,
                                                   float* __restrict__ hs,
                                                   int t)
{
    int tid  = threadIdx.x;
    int b    = tid >> 5;          // 0..7
    int gate = (tid >> 3) & 3;    // 0..3
    int jl   = (tid >> 1) & 3;    // 0..3
    int ks   = tid & 1;           // 0..1
    int j0   = blockIdx.x * 4;
    int col  = gate*HID + j0 + jl;

    float acc = 0.0f;
    if (t > 0) {
        const float4* hv = (const float4*)(hs + ((size_t)b*SEQ + (t-1))*HID)
                           + ks * (HID/8);
        const float4* wv = (const float4*)(WT + (size_t)col*HID)
                           + ks * (HID/8);
        #pragma unroll 8
        for (int k4 = 0; k4 < HID/8; ++k4) {
            float4 h4 = hv[k4];
            float4 w4 = wv[k4];
            acc += h4.x*w4.x + h4.y*w4.y + h4.z*w4.z + h4.w*w4.w;
        }
    }
    acc += __shfl_xor(acc, 1);

    __shared__ float g_sm[BATCH][4][4];
    if (ks == 0)
        g_sm[b][gate][jl] = acc + xg[(size_t)(b*SEQ + t)*GD + col];
    __syncthreads();

    if (tid < 32) {
        int bb = tid >> 2;
        int j  = tid & 3;
        float iv = g_sm[bb][0][j];
        float fv = g_sm[bb][1][j];
        float gv = g_sm[bb][2][j];
        float ov = g_sm[bb][3][j];
        iv = 1.0f / (1.0f + expf(-iv));
        fv = 1.0f / (1.0f + expf(-fv));
        gv = tanhf(gv);
        ov = 1.0f / (1.0f + expf(-ov));
        float c  = (t > 0) ? c_state[(size_t)bb*HID + j0 + j] : 0.0f;
        float cn = fv*c + iv*gv;
        float hn = ov * tanhf(cn);
        c_state[(size_t)bb*HID + j0 + j] = cn;
        hs[((size_t)bb*SEQ + t)*HID + j0 + j] = hn;
    }
}

// ---------------------------------------------------------------------------
// Launch
// ---------------------------------------------------------------------------
extern "C" void kernel_launch(void* const* d_in, const int* in_sizes, int n_in,
                              void* d_out, int out_size, void* d_ws, size_t ws_size,
                              hipStream_t stream)
{
    const int*   ids    = (const int*)  d_in[0];
    const float* w_out  = (const float*)d_in[1];
    const float* b_out  = (const float*)d_in[2];
    const float* W_ih   = (const float*)d_in[3];
    const float* W_hh   = (const float*)d_in[4];
    const float* b_lstm = (const float*)d_in[5];
    float* out = (float*)d_out;

    // Scratch carved from d_out (524 MB; every region dead before the final
    // GEMM overwrites d_out). hs (read during the final GEMM) lives in d_ws.
    char* ob = (char*)d_out;
    float* emb    = (float*)(ob);                 // 16,777,216 B
    float* WT     = (float*)(ob + 16777216);      // 16,777,216 B
    float* xg     = (float*)(ob + 33554432);      // 67,108,864 B
    float* cstate = (float*)(ob + 100663296);     // 32,768 B
    float* hs     = (float*)d_ws;                 // 16,777,216 B

    // 1) embedding gather
    k_gather<<<ROWS, 256, 0, stream>>>(ids, w_out, emb);

    // 2) transpose W_hh for contiguous per-column dots in the scan
    k_transpose<<<dim3(GD/32, HID/32), dim3(32, 8), 0, stream>>>(W_hh, WT);

    // 3) x_gates = emb @ W_ih + b_lstm   [4096 x 4096]  (split-bf16 MFMA)
    k_gemm_mfma<<<dim3(GD/GBN, ROWS/GBM), 256, 0, stream>>>(
        emb, W_ih, b_lstm, xg, ROWS, GD, HID);

    // 4) sequential LSTM scan: 512 launches, race-free
    for (int t = 0; t < SEQ; ++t)
        k_lstm_step<<<HID/4, 256, 0, stream>>>(xg, WT, cstate, hs, t);

    // 5) logits = hs @ w_out + b_out   [4096 x 32000]  (split-bf16 MFMA)
    k_gemm_mfma<<<dim3(VOCAB/GBN, ROWS/GBM), 256, 0, stream>>>(
        hs, w_out, b_out, out, ROWS, VOCAB, HID);
}

// Round 4
// 5170.047 us; speedup vs baseline: 3.1665x; 2.6111x over previous
//
#include <hip/hip_runtime.h>
#include <math.h>

#define VOCAB 32000
#define HID   1024
#define BATCH 8
#define SEQ   512
#define GD    (4*HID)       // 4096 gate width
#define ROWS  (BATCH*SEQ)   // 4096

typedef __attribute__((ext_vector_type(8))) short short8;
typedef __attribute__((ext_vector_type(4))) float f32x4;

// ---------------------------------------------------------------------------
// 1) Embedding gather: emb[row][h] = w_out[h][ids[row]]
// ---------------------------------------------------------------------------
__global__ __launch_bounds__(256) void k_gather(const int* __restrict__ ids,
                                                const float* __restrict__ w_out,
                                                float* __restrict__ emb)
{
    int row = blockIdx.x;            // 0..4095  (b*SEQ + s)
    int id  = ids[row];
    const float* src = w_out + id;   // column id, stride VOCAB
    float* dst = emb + (size_t)row * HID;
    for (int h = threadIdx.x; h < HID; h += 256)
        dst[h] = src[(size_t)h * VOCAB];
}

// ---------------------------------------------------------------------------
// 2) Transpose W_hh [1024][4096] -> W_hhT [4096][1024]
// ---------------------------------------------------------------------------
__global__ __launch_bounds__(256) void k_transpose(const float* __restrict__ W,
                                                   float* __restrict__ WT)
{
    __shared__ float tile[32][33];
    int bx = blockIdx.x;
    int by = blockIdx.y;
    int x = bx*32 + threadIdx.x;
    int y = by*32 + threadIdx.y;
    #pragma unroll
    for (int i = 0; i < 32; i += 8)
        tile[threadIdx.y + i][threadIdx.x] = W[(size_t)(y + i)*GD + x];
    __syncthreads();
    int k   = by*32 + threadIdx.x;
    int col = bx*32 + threadIdx.y;
    #pragma unroll
    for (int i = 0; i < 32; i += 8)
        WT[(size_t)(col + i)*HID + k] = tile[threadIdx.x][threadIdx.y + i];
}

// ---------------------------------------------------------------------------
// 3) Split-bf16 MFMA GEMM + bias:  C = A(f32)·B(f32) + bias
//    C ≈ Ahi·Bhi + Ahi·Blo + Alo·Bhi   (err ~2^-16 rel)
//    Block: 256 thr = 4 waves (2x2), 128x128 tile, BK=32.
// ---------------------------------------------------------------------------
#define GBM 128
#define GBN 128
#define GBK 32

__device__ __forceinline__ unsigned pack_hi(float x, float y) {
    return (__float_as_uint(x) >> 16) | (__float_as_uint(y) & 0xFFFF0000u);
}
__device__ __forceinline__ float hi_f32(float x) {
    return __uint_as_float(__float_as_uint(x) & 0xFFFF0000u);
}
// packed word: hi bf16 in high half, lo bf16 in low half
__device__ __forceinline__ unsigned pack_pair(float x) {
    unsigned hb = __float_as_uint(x) & 0xFFFF0000u;
    float lo = x - __uint_as_float(hb);
    return hb | (__float_as_uint(lo) >> 16);
}

__global__ __launch_bounds__(256) void k_gemm_mfma(const float* __restrict__ A,
                                                   const float* __restrict__ B,
                                                   const float* __restrict__ bias,
                                                   float* __restrict__ C,
                                                   int M, int N, int K)
{
    __shared__ unsigned short As_hi[GBM][40];
    __shared__ unsigned short As_lo[GBM][40];
    __shared__ unsigned int   Bs[GBK][130];

    int tid  = threadIdx.x;
    int brow = blockIdx.y * GBM;
    int bcol = blockIdx.x * GBN;

    int lane = tid & 63;
    int wid  = tid >> 6;
    int wm   = wid >> 1;
    int wn   = wid & 1;
    int l15  = lane & 15;
    int l4   = lane >> 4;

    int a_m = tid >> 3;
    int a_c = tid & 7;
    int b_k = tid >> 5;
    int b_n = tid & 31;

    f32x4 acc[4][4] = {};

    for (int k0 = 0; k0 < K; k0 += GBK) {
        #pragma unroll
        for (int p = 0; p < 4; ++p) {
            int r = a_m + p*32;
            float4 v = *(const float4*)(A + (size_t)(brow + r)*K + k0 + a_c*4);
            unsigned h0 = pack_hi(v.x, v.y);
            unsigned h1 = pack_hi(v.z, v.w);
            float lx = v.x - hi_f32(v.x);
            float ly = v.y - hi_f32(v.y);
            float lz = v.z - hi_f32(v.z);
            float lw = v.w - hi_f32(v.w);
            unsigned l0 = pack_hi(lx, ly);
            unsigned l1 = pack_hi(lz, lw);
            *(uint2*)&As_hi[r][a_c*4] = make_uint2(h0, h1);
            *(uint2*)&As_lo[r][a_c*4] = make_uint2(l0, l1);
        }
        #pragma unroll
        for (int p = 0; p < 4; ++p) {
            int kk = b_k + p*8;
            float4 v = *(const float4*)(B + (size_t)(k0 + kk)*N + bcol + b_n*4);
            unsigned w0 = pack_pair(v.x);
            unsigned w1 = pack_pair(v.y);
            unsigned w2 = pack_pair(v.z);
            unsigned w3 = pack_pair(v.w);
            *(uint2*)&Bs[kk][b_n*4]     = make_uint2(w0, w1);
            *(uint2*)&Bs[kk][b_n*4 + 2] = make_uint2(w2, w3);
        }
        __syncthreads();

        short8 ah[4], al[4];
        #pragma unroll
        for (int m = 0; m < 4; ++m) {
            int r = wm*64 + m*16 + l15;
            ah[m] = *(const short8*)&As_hi[r][l4*8];
            al[m] = *(const short8*)&As_lo[r][l4*8];
        }

        #pragma unroll
        for (int n = 0; n < 4; ++n) {
            int col = wn*64 + n*16 + l15;
            unsigned w[8];
            #pragma unroll
            for (int j = 0; j < 8; ++j)
                w[j] = Bs[l4*8 + j][col];
            union { short8 v; unsigned d[4]; } bh, bl;
            #pragma unroll
            for (int d = 0; d < 4; ++d) {
                bh.d[d] = (w[2*d] >> 16)      | (w[2*d+1] & 0xFFFF0000u);
                bl.d[d] = (w[2*d] & 0xFFFFu)  | (w[2*d+1] << 16);
            }
            #pragma unroll
            for (int m = 0; m < 4; ++m) {
                acc[m][n] = __builtin_amdgcn_mfma_f32_16x16x32_bf16(ah[m], bh.v, acc[m][n], 0, 0, 0);
                acc[m][n] = __builtin_amdgcn_mfma_f32_16x16x32_bf16(ah[m], bl.v, acc[m][n], 0, 0, 0);
                acc[m][n] = __builtin_amdgcn_mfma_f32_16x16x32_bf16(al[m], bh.v, acc[m][n], 0, 0, 0);
            }
        }
        __syncthreads();
    }

    #pragma unroll
    for (int n = 0; n < 4; ++n) {
        int col = bcol + wn*64 + n*16 + l15;
        float bv = bias[col];
        #pragma unroll
        for (int m = 0; m < 4; ++m) {
            int rb = brow + wm*64 + m*16 + l4*4;
            #pragma unroll
            for (int r = 0; r < 4; ++r)
                C[(size_t)(rb + r)*N + col] = acc[m][n][r] + bv;
        }
    }
}

// ---------------------------------------------------------------------------
// 4) One LSTM timestep — rewritten for occupancy + coalescing.
//    Grid: 1024 blocks (1 hidden col j each) x 256 thr (wave = gate).
//    Wave reads its WT column fully coalesced (lane-split over K), keeps
//    8 per-batch accumulators in registers, butterfly-reduces over lanes.
//    Race-free: reads hs[t-1] rows, writes hs[t] rows (disjoint).
// ---------------------------------------------------------------------------
__global__ __launch_bounds__(256) void k_lstm_step(const float* __restrict__ xg,
                                                   const float* __restrict__ WT,
                                                   float* __restrict__ c_state,
                                                   float* __restrict__ hs,
                                                   int t)
{
    int j    = blockIdx.x;            // hidden col 0..1023
    int gate = threadIdx.x >> 6;      // 0..3 (i,f,g,o)
    int lane = threadIdx.x & 63;
    int col  = gate*HID + j;

    float acc[8] = {};
    if (t > 0) {
        const float4* wv = (const float4*)(WT + (size_t)col*HID);
        #pragma unroll
        for (int c = 0; c < 4; ++c) {
            int k4 = c*64 + lane;     // coalesced: consecutive lanes -> consecutive float4
            float4 w4 = wv[k4];
            #pragma unroll
            for (int b = 0; b < 8; ++b) {
                float4 h4 = ((const float4*)(hs + ((size_t)b*SEQ + (t-1))*HID))[k4];
                acc[b] += w4.x*h4.x + w4.y*h4.y + w4.z*h4.z + w4.w*h4.w;
            }
        }
        #pragma unroll
        for (int b = 0; b < 8; ++b) {
            acc[b] += __shfl_xor(acc[b], 32);
            acc[b] += __shfl_xor(acc[b], 16);
            acc[b] += __shfl_xor(acc[b], 8);
            acc[b] += __shfl_xor(acc[b], 4);
            acc[b] += __shfl_xor(acc[b], 2);
            acc[b] += __shfl_xor(acc[b], 1);
        }
    }

    __shared__ float g_sm[4][8];
    if (lane == 0) {
        #pragma unroll
        for (int b = 0; b < 8; ++b)
            g_sm[gate][b] = acc[b];
    }
    __syncthreads();

    if (threadIdx.x < 8) {
        int b = threadIdx.x;
        size_t xbase = ((size_t)b*SEQ + t)*GD + j;
        float iv = g_sm[0][b] + xg[xbase];
        float fv = g_sm[1][b] + xg[xbase + HID];
        float gv = g_sm[2][b] + xg[xbase + 2*HID];
        float ov = g_sm[3][b] + xg[xbase + 3*HID];
        iv = 1.0f / (1.0f + expf(-iv));
        fv = 1.0f / (1.0f + expf(-fv));
        gv = tanhf(gv);
        ov = 1.0f / (1.0f + expf(-ov));
        float c  = (t > 0) ? c_state[(size_t)b*HID + j] : 0.0f;
        float cn = fv*c + iv*gv;
        float hn = ov * tanhf(cn);
        c_state[(size_t)b*HID + j] = cn;
        hs[((size_t)b*SEQ + t)*HID + j] = hn;
    }
}

// ---------------------------------------------------------------------------
// Launch
// ---------------------------------------------------------------------------
extern "C" void kernel_launch(void* const* d_in, const int* in_sizes, int n_in,
                              void* d_out, int out_size, void* d_ws, size_t ws_size,
                              hipStream_t stream)
{
    const int*   ids    = (const int*)  d_in[0];
    const float* w_out  = (const float*)d_in[1];
    const float* b_out  = (const float*)d_in[2];
    const float* W_ih   = (const float*)d_in[3];
    const float* W_hh   = (const float*)d_in[4];
    const float* b_lstm = (const float*)d_in[5];
    float* out = (float*)d_out;

    // Scratch carved from d_out (524 MB; every region dead before the final
    // GEMM overwrites d_out). hs (read during the final GEMM) lives in d_ws.
    char* ob = (char*)d_out;
    float* emb    = (float*)(ob);                 // 16,777,216 B
    float* WT     = (float*)(ob + 16777216);      // 16,777,216 B
    float* xg     = (float*)(ob + 33554432);      // 67,108,864 B
    float* cstate = (float*)(ob + 100663296);     // 32,768 B
    float* hs     = (float*)d_ws;                 // 16,777,216 B

    // 1) embedding gather
    k_gather<<<ROWS, 256, 0, stream>>>(ids, w_out, emb);

    // 2) transpose W_hh for contiguous per-column dots in the scan
    k_transpose<<<dim3(GD/32, HID/32), dim3(32, 8), 0, stream>>>(W_hh, WT);

    // 3) x_gates = emb @ W_ih + b_lstm   [4096 x 4096]  (split-bf16 MFMA)
    k_gemm_mfma<<<dim3(GD/GBN, ROWS/GBM), 256, 0, stream>>>(
        emb, W_ih, b_lstm, xg, ROWS, GD, HID);

    // 4) sequential LSTM scan: 512 launches, race-free
    for (int t = 0; t < SEQ; ++t)
        k_lstm_step<<<HID, 256, 0, stream>>>(xg, WT, cstate, hs, t);

    // 5) logits = hs @ w_out + b_out   [4096 x 32000]  (split-bf16 MFMA)
    k_gemm_mfma<<<dim3(VOCAB/GBN, ROWS/GBM), 256, 0, stream>>>(
        hs, w_out, b_out, out, ROWS, VOCAB, HID);
}